// Round 1
// baseline (104.775 us; speedup 1.0000x reference)
//
#include <hip/hip_runtime.h>
#include <math.h>

// Problem: MinibatchDiscrimination
//   B=512, IN=512, OUT=100, KDIM=5
//   M = x @ T.view(512,500)            [512,500] fp32
//   o_b[j,o] = sum_i exp(-sum_k |M[i,o,k]-M[j,o,k]|) - 1   [512,100]

#define NB    512
#define NIN   512
#define NOUT  100
#define KDIM  5
#define NCOL  (NOUT*KDIM)   // 500

// ---------------- Kernel 1: fp32 GEMM C[512,500] = A[512,512]*B[512,500]
// 32x32 tile, K-chunk 32, 16x16 threads each computing 2x2.
__global__ __launch_bounds__(256) void gemm_kernel(const float* __restrict__ A,
                                                   const float* __restrict__ Bm,
                                                   float* __restrict__ C) {
    __shared__ float As[32][33];
    __shared__ float Bs[32][33];
    const int tx = threadIdx.x;        // 0..15
    const int ty = threadIdx.y;        // 0..15
    const int tid = ty * 16 + tx;
    const int bm = blockIdx.y * 32;
    const int bn = blockIdx.x * 32;

    float acc00 = 0.f, acc01 = 0.f, acc10 = 0.f, acc11 = 0.f;

    for (int kt = 0; kt < NIN; kt += 32) {
        #pragma unroll
        for (int l = 0; l < 4; ++l) {
            int idx = tid + l * 256;
            int r = idx >> 5, c = idx & 31;
            As[r][c] = A[(bm + r) * NIN + kt + c];
            int col = bn + c;
            Bs[r][c] = (col < NCOL) ? Bm[(kt + r) * NCOL + col] : 0.0f;
        }
        __syncthreads();
        #pragma unroll
        for (int k = 0; k < 32; ++k) {
            float a0 = As[ty * 2][k],     a1 = As[ty * 2 + 1][k];
            float b0 = Bs[k][tx * 2],     b1 = Bs[k][tx * 2 + 1];
            acc00 += a0 * b0; acc01 += a0 * b1;
            acc10 += a1 * b0; acc11 += a1 * b1;
        }
        __syncthreads();
    }

    const int row0 = bm + ty * 2;
    const int col0 = bn + tx * 2;
    if (col0 < NCOL) {
        C[row0 * NCOL + col0]       = acc00;
        C[(row0 + 1) * NCOL + col0] = acc10;
    }
    if (col0 + 1 < NCOL) {
        C[row0 * NCOL + col0 + 1]       = acc01;
        C[(row0 + 1) * NCOL + col0 + 1] = acc11;
    }
}

// ---------------- Kernel 2: pairwise L1 + exp + reduce over i.
// Block = (o, j-chunk of 128). 256 threads: thread owns one j, half the
// i-range (256 iters). M[:,o,0:5] staged in LDS padded to 8 floats/row so
// float4 reads are 32B-aligned (ds_read_b128 + ds_read_b32, broadcast).
__global__ __launch_bounds__(256) void pairwise_kernel(const float* __restrict__ M,
                                                       float* __restrict__ out) {
    __shared__ float Ms[NB * 8];      // 16 KiB
    __shared__ float partial[256];

    const int o   = blockIdx.x;       // 0..99
    const int jc  = blockIdx.y;       // 0..3
    const int tid = threadIdx.x;      // 0..255

    // stage M[:, o, 0:5] -> Ms[b*8 + k]
    for (int b = tid; b < NB; b += 256) {
        const float* src = M + b * NCOL + o * KDIM;
        float* dst = Ms + b * 8;
        dst[0] = src[0]; dst[1] = src[1]; dst[2] = src[2];
        dst[3] = src[3]; dst[4] = src[4];
    }
    __syncthreads();

    const int j  = jc * 128 + (tid & 127);
    const int i0 = (tid >> 7) * 256;

    const float4 jv = *reinterpret_cast<const float4*>(&Ms[j * 8]);
    const float  j4 = Ms[j * 8 + 4];

    float acc = 0.0f;
    #pragma unroll 4
    for (int i = i0; i < i0 + 256; ++i) {
        float4 v = *reinterpret_cast<const float4*>(&Ms[i * 8]);
        float v4 = Ms[i * 8 + 4];
        float norm = fabsf(v.x - jv.x) + fabsf(v.y - jv.y) + fabsf(v.z - jv.z)
                   + fabsf(v.w - jv.w) + fabsf(v4 - j4);
        acc += __expf(-norm);
    }

    partial[tid] = acc;
    __syncthreads();

    if (tid < 128) {
        // i==j self-term contributes exp(0)=1 exactly; reference subtracts it.
        float tot = partial[tid] + partial[tid + 128] - 1.0f;
        out[j * NOUT + o] = tot;   // out is [512,100] row-major
    }
}

extern "C" void kernel_launch(void* const* d_in, const int* in_sizes, int n_in,
                              void* d_out, int out_size, void* d_ws, size_t ws_size,
                              hipStream_t stream) {
    const float* x = (const float*)d_in[0];   // [512,512]
    const float* T = (const float*)d_in[1];   // [512,100,5] == [512,500]
    float* M   = (float*)d_ws;                // 512*500*4 = 1.024 MB scratch
    float* out = (float*)d_out;               // [512,100]

    dim3 g1(16, 16), b1(16, 16);
    gemm_kernel<<<g1, b1, 0, stream>>>(x, T, M);

    dim3 g2(NOUT, 4);
    pairwise_kernel<<<g2, 256, 0, stream>>>(M, out);
}

// Round 2
// 85.520 us; speedup vs baseline: 1.2252x; 1.2252x over previous
//
#include <hip/hip_runtime.h>
#include <math.h>

// MinibatchDiscrimination: B=512, IN=512, OUT=100, K=5
//   M = x @ T.view(512,500)                      [512,500]
//   out[j,o] = sum_i exp(-sum_k |M[i,o,k]-M[j,o,k]|) - 1    [512,100]
//
// Pipeline:
//  k1 gemm   : K-split x8, 64x64 tiles, 4x4 micro -> Mpart[8][512][500]  (512 blocks)
//  k2 reduce : sum 8 partials -> M8[512][800] (o-padded: M8[b][o*8+k])   (250 blocks)
//  k3 pair   : per (o, j-chunk64) block, LDS-staged i-loop                (800 blocks)

#define NB    512
#define NIN   512
#define NOUT  100
#define KDIM  5
#define NCOL  (NOUT*KDIM)       // 500
#define KZ    8                 // K-split factor
#define MP_ELEMS (NB*NCOL)      // 256000 per partial
#define M8_LD 800               // padded row stride of M8

// ---------------- Kernel 1: partial GEMM, 64x64 tile, K=64 per block
__global__ __launch_bounds__(256) void gemm_kernel(const float* __restrict__ A,
                                                   const float* __restrict__ Bm,
                                                   float* __restrict__ Mpart) {
    // pad 68 words: keeps float4 rows 16B-aligned (68*4=272, 272%16==0)
    __shared__ float As[64][68];
    __shared__ float Bs[64][68];

    const int tx = threadIdx.x;            // 0..15
    const int ty = threadIdx.y;            // 0..15
    const int tid = ty * 16 + tx;
    const int bn = blockIdx.x * 64;        // n-tile
    const int bm = blockIdx.y * 64;        // m-tile
    const int kz = blockIdx.z;             // 0..7
    const int kt = kz * 64;

    // stage A tile: 64 rows x 64 k = 1024 float4
    #pragma unroll
    for (int l = 0; l < 4; ++l) {
        int idx = tid + l * 256;
        int row = idx >> 4, q = idx & 15;
        float4 v = *reinterpret_cast<const float4*>(&A[(bm + row) * NIN + kt + q * 4]);
        *reinterpret_cast<float4*>(&As[row][q * 4]) = v;
    }
    // stage B tile: 64 k-rows x 64 n
    #pragma unroll
    for (int l = 0; l < 4; ++l) {
        int idx = tid + l * 256;
        int row = idx >> 4, q = idx & 15;
        int col = bn + q * 4;
        float4 v;
        if (col + 3 < NCOL) {
            v = *reinterpret_cast<const float4*>(&Bm[(kt + row) * NCOL + col]);
        } else {
            v.x = (col + 0 < NCOL) ? Bm[(kt + row) * NCOL + col + 0] : 0.f;
            v.y = (col + 1 < NCOL) ? Bm[(kt + row) * NCOL + col + 1] : 0.f;
            v.z = (col + 2 < NCOL) ? Bm[(kt + row) * NCOL + col + 2] : 0.f;
            v.w = (col + 3 < NCOL) ? Bm[(kt + row) * NCOL + col + 3] : 0.f;
        }
        *reinterpret_cast<float4*>(&Bs[row][q * 4]) = v;
    }
    __syncthreads();

    float acc[4][4];
    #pragma unroll
    for (int i = 0; i < 4; ++i)
        #pragma unroll
        for (int j = 0; j < 4; ++j) acc[i][j] = 0.f;

    #pragma unroll 4
    for (int k = 0; k < 64; ++k) {
        float a[4], b[4];
        #pragma unroll
        for (int i = 0; i < 4; ++i) a[i] = As[ty * 4 + i][k];
        #pragma unroll
        for (int j = 0; j < 4; ++j) b[j] = Bs[k][tx * 4 + j];
        #pragma unroll
        for (int i = 0; i < 4; ++i)
            #pragma unroll
            for (int j = 0; j < 4; ++j) acc[i][j] += a[i] * b[j];
    }

    float* C = Mpart + kz * MP_ELEMS;
    #pragma unroll
    for (int i = 0; i < 4; ++i) {
        int row = bm + ty * 4 + i;
        int col0 = bn + tx * 4;
        if (col0 + 3 < NCOL) {
            float4 v = make_float4(acc[i][0], acc[i][1], acc[i][2], acc[i][3]);
            *reinterpret_cast<float4*>(&C[row * NCOL + col0]) = v;
        } else {
            #pragma unroll
            for (int j = 0; j < 4; ++j)
                if (col0 + j < NCOL) C[row * NCOL + col0 + j] = acc[i][j];
        }
    }
}

// ---------------- Kernel 2: sum KZ partials -> M8[512][800] (M8[b][o*8+k])
__global__ __launch_bounds__(256) void reduce_kernel(const float* __restrict__ Mpart,
                                                     float* __restrict__ M8) {
    const unsigned gtid = blockIdx.x * 256 + threadIdx.x;   // 64000 threads
    for (unsigned n = gtid; n < MP_ELEMS; n += 64000) {
        unsigned b = n / NCOL;
        unsigned c = n - b * NCOL;
        unsigned o = c / KDIM;
        unsigned k = c - o * KDIM;
        float s = 0.f;
        #pragma unroll
        for (int z = 0; z < KZ; ++z) s += Mpart[z * MP_ELEMS + n];
        M8[b * M8_LD + o * 8 + k] = s;
    }
}

// ---------------- Kernel 3: pairwise L1 + exp + reduce over i
// grid (100, 8): block = (o, 64 j's). 256 threads = 64 j x 4 i-splits.
__global__ __launch_bounds__(256) void pairwise_kernel(const float* __restrict__ M8,
                                                       float* __restrict__ out) {
    __shared__ float Ms[NB * 8];      // 16 KiB
    __shared__ float partial[256];

    const int o   = blockIdx.x;       // 0..99
    const int jc  = blockIdx.y;       // 0..7
    const int tid = threadIdx.x;      // 0..255

    // stage M8[:, o*8 .. o*8+7] -> Ms (two aligned float4 per row)
    for (int b = tid; b < NB; b += 256) {
        const float* src = M8 + b * M8_LD + o * 8;
        float4 v0 = *reinterpret_cast<const float4*>(src);
        float4 v1 = *reinterpret_cast<const float4*>(src + 4);
        *reinterpret_cast<float4*>(&Ms[b * 8])     = v0;
        *reinterpret_cast<float4*>(&Ms[b * 8 + 4]) = v1;
    }
    __syncthreads();

    const int j  = jc * 64 + (tid & 63);
    const int i0 = (tid >> 6) * 128;

    const float4 jv = *reinterpret_cast<const float4*>(&Ms[j * 8]);
    const float  j4 = Ms[j * 8 + 4];

    float acc = 0.0f;
    #pragma unroll 4
    for (int i = i0; i < i0 + 128; ++i) {
        float4 v = *reinterpret_cast<const float4*>(&Ms[i * 8]);
        float v4 = Ms[i * 8 + 4];
        float norm = fabsf(v.x - jv.x) + fabsf(v.y - jv.y) + fabsf(v.z - jv.z)
                   + fabsf(v.w - jv.w) + fabsf(v4 - j4);
        acc += __expf(-norm);
    }

    partial[tid] = acc;
    __syncthreads();

    if (tid < 64) {
        float tot = partial[tid] + partial[tid + 64] + partial[tid + 128]
                  + partial[tid + 192] - 1.0f;   // remove exp(0) self-term
        out[(jc * 64 + tid) * NOUT + o] = tot;
    }
}

extern "C" void kernel_launch(void* const* d_in, const int* in_sizes, int n_in,
                              void* d_out, int out_size, void* d_ws, size_t ws_size,
                              hipStream_t stream) {
    const float* x = (const float*)d_in[0];   // [512,512]
    const float* T = (const float*)d_in[1];   // [512,500]
    float* Mpart = (float*)d_ws;                          // 8 * 1.024 MB
    float* M8    = (float*)d_ws + KZ * MP_ELEMS;          // 512*800*4 = 1.6 MB
    float* out   = (float*)d_out;                         // [512,100]

    gemm_kernel<<<dim3(8, 8, KZ), dim3(16, 16), 0, stream>>>(x, T, Mpart);
    reduce_kernel<<<250, 256, 0, stream>>>(Mpart, M8);
    pairwise_kernel<<<dim3(NOUT, 8), 256, 0, stream>>>(M8, out);
}